// Round 1
// baseline (322.743 us; speedup 1.0000x reference)
//
#include <hip/hip_runtime.h>

typedef unsigned short u16;
typedef unsigned int   u32;
typedef unsigned long long u64;

typedef __attribute__((ext_vector_type(8))) short short8;
typedef __attribute__((ext_vector_type(4))) float f32x4;

#define DEV static __device__ __forceinline__

// POW10F[p][k] = 10^k mod p  (primes 7,11,13,17,19,23,29,31,37)
__constant__ float POW10F[9][10] = {
  {1,3,2,6,4,5,1,3,2,6},
  {1,10,1,10,1,10,1,10,1,10},
  {1,10,9,12,3,4,1,10,9,12},
  {1,10,15,14,4,6,9,5,16,7},
  {1,10,5,12,6,3,11,15,17,18},
  {1,10,8,11,18,19,6,14,2,20},
  {1,10,13,14,24,8,22,17,25,18},
  {1,10,7,8,18,25,2,20,14,16},
  {1,10,26,1,10,26,1,10,26,1},
};

#define M_TOTAL  247357937827ull
#define M_HALF   123678968913ull

DEV u16 f2bf_rne(float f){
  u32 u = __float_as_uint(f);
  return (u16)((u + 0x7FFFu + ((u >> 16) & 1u)) >> 16);
}
DEV float bf2f(u16 v){ return __uint_as_float(((u32)v) << 16); }

DEV short8 pack_bf16(float4 a, float4 b){
  union { short8 s; u32 u[4]; } r;
  r.u[0] = (__float_as_uint(a.x) >> 16) | (__float_as_uint(a.y) & 0xFFFF0000u);
  r.u[1] = (__float_as_uint(a.z) >> 16) | (__float_as_uint(a.w) & 0xFFFF0000u);
  r.u[2] = (__float_as_uint(b.x) >> 16) | (__float_as_uint(b.y) & 0xFFFF0000u);
  r.u[3] = (__float_as_uint(b.z) >> 16) | (__float_as_uint(b.w) & 0xFFFF0000u);
  return r.s;
}

DEV void load_lds16(const void* g, void* l){
  __builtin_amdgcn_global_load_lds((const __attribute__((address_space(1))) void*)g,
                                   (__attribute__((address_space(3))) void*)l, 16, 0, 0);
}

DEV int modpow6(int b, int e, int p){
  int res = 1; b %= p;
  #pragma unroll
  for (int i = 0; i < 6; ++i){
    if (e & 1) res = (res * b) % p;
    b = (b * b) % p;
    e >>= 1;
  }
  return res;
}

// ---------------- prelude: per-batch scan (blocks 0..15) + weight repack (16..76) ----------------
__global__ void prelude_kernel(const int* __restrict__ ids, const float* __restrict__ W1,
                               const float* __restrict__ W2, int* __restrict__ op_idx,
                               float* __restrict__ has_eq, u16* __restrict__ w1f,
                               u16* __restrict__ w2f){
  __shared__ int smin[256];
  __shared__ int seq[256];
  int bid = blockIdx.x, tid = threadIdx.x;
  if (bid < 16){
    int b = bid;
    int best = 2048, eq = 0;
    for (int i = tid; i < 2048; i += 256){
      int t = ids[b * 2048 + i];
      if (t >= 20 && t < 25) best = min(best, i);
      eq |= (t == 28) ? 1 : 0;
    }
    smin[tid] = best; seq[tid] = eq;
    __syncthreads();
    for (int s = 128; s > 0; s >>= 1){
      if (tid < s){ smin[tid] = min(smin[tid], smin[tid + s]); seq[tid] |= seq[tid + s]; }
      __syncthreads();
    }
    if (tid == 0){
      int op = -1;
      if (smin[0] < 2048) op = ids[b * 2048 + smin[0]] - 20;
      op_idx[b] = op;
      has_eq[b] = seq[0] ? 1.0f : 0.0f;
    }
  } else {
    int t = (bid - 16) * 256 + tid;   // 0..15615
    if (t < 12288){
      int blk = t >> 6, L = t & 63;
      int T = blk >> 3, b = blk & 7;
      int q = L >> 4, ln = L & 15;
      #pragma unroll
      for (int j = 0; j < 8; ++j){
        int k = 32 * T + 8 * q + j;
        int n = 16 * b + ln;
        w1f[(size_t)blk * 512 + L * 8 + j] = f2bf_rne(W1[k * 128 + n]);
      }
    } else {
      int t2 = t - 12288;             // 0..3327
      int blk = t2 >> 6, L = t2 & 63;
      int ts = blk / 13, b2 = blk % 13;
      int q = L >> 4, ln = L & 15;
      #pragma unroll
      for (int j = 0; j < 8; ++j){
        int k = 32 * ts + 8 * q + j;
        int n = 16 * b2 + ln;
        w2f[(size_t)blk * 512 + L * 8 + j] = (n < 200) ? f2bf_rne(W2[k * 200 + n]) : (u16)0;
      }
    }
  }
}

// ---------------- mega: 32-token blocks, 4 blocks/CU ----------------
// LDS 40960B: wbuf = 2x16KB W1 K-chunk dbuf (buf0 later reused as logits [32][212] bf16)
//             tail 8KB: hidf [2][2048] u16 (GEMM2 A-frags) -> digits/tab/ops/msbv overlay
__launch_bounds__(256, 4)
__global__ void mega_kernel(const float* __restrict__ h, const u16* __restrict__ w1f,
                            const u16* __restrict__ w2f, const float* __restrict__ b1,
                            const float* __restrict__ b2, const float* __restrict__ Winj,
                            const float* __restrict__ binj, const float* __restrict__ gate,
                            const int* __restrict__ op_idx_ws, const float* __restrict__ has_eq_ws,
                            float* __restrict__ dout){
  __shared__ __align__(16) char lds[40960];
  u16*   wbuf     = (u16*)lds;                 // 16384 u16 (2 x 8192)
  char*  tail     = lds + 32768;
  u16*   hidf     = (u16*)tail;                // [2][2048] u16 = 8192B
  float* digits_s = (float*)tail;              // [32][20] 2560B (overlays hidf, dead by then)
  float* tab_s    = (float*)(tail + 2560);     // [32][18] 2304B
  u64*   ops_s    = (u64*)(tail + 4864);       // [32][5]  1280B
  float* msbv     = (float*)(tail + 6144);     // [32][12] 1536B

  const int tid  = threadIdx.x;
  const int w    = tid >> 6;
  const int lane = tid & 63;
  const int ln   = lane & 15, q = lane >> 4;
  const int m    = w & 1;        // M-tile (16 tokens each)
  const int nh   = w >> 1;       // N-half of GEMM1 (64 cols each)
  const int wg   = blockIdx.x;
  const int tok0 = wg * 32;
  const int gtok = tok0 + m * 16 + ln;
  const int batch = wg >> 6;     // 64 blocks per batch

  const int   op = op_idx_ws[batch];
  const float G  = has_eq_ws[batch] * (1.0f / (1.0f + __expf(-gate[0])));

  float b1v[4];
  #pragma unroll
  for (int b = 0; b < 4; ++b) b1v[b] = b1[nh * 64 + 16 * b + ln];

  // ---- GEMM1: hid = relu(h @ W1 + b1); 12 K-chunks of 64, dbuf, ONE barrier per chunk ----
  f32x4 acc[4];
  #pragma unroll
  for (int b = 0; b < 4; ++b) acc[b] = (f32x4)0.0f;

  const float4* ap = (const float4*)(h + (size_t)gtok * 768);
  float4 xa[2], xb[2];
  // prologue: stage chunk 0 into buf0, load h chunk 0
  #pragma unroll
  for (int i = 0; i < 4; ++i){
    int bl = w * 4 + i;                 // 16 blocks of 1KB per chunk: T = c*2 + (bl>>3), b = bl&7
    load_lds16(w1f + (size_t)(((bl >> 3)) * 8 + (bl & 7)) * 512 + lane * 8,
               wbuf + bl * 512);
  }
  #pragma unroll
  for (int t = 0; t < 2; ++t){ xa[t] = ap[t * 8 + q * 2]; xb[t] = ap[t * 8 + q * 2 + 1]; }

  #pragma unroll
  for (int c = 0; c < 12; ++c){
    __syncthreads();                    // drains chunk-c staging + chunk-c h loads
    const u16* cur = wbuf + (c & 1) * 8192;
    if (c < 11){
      u16* nxt = wbuf + ((c + 1) & 1) * 8192;
      #pragma unroll
      for (int i = 0; i < 4; ++i){
        int bl = w * 4 + i;
        int T  = (c + 1) * 2 + (bl >> 3);
        load_lds16(w1f + (size_t)(T * 8 + (bl & 7)) * 512 + lane * 8, nxt + bl * 512);
      }
    }
    short8 af[2];
    #pragma unroll
    for (int t = 0; t < 2; ++t) af[t] = pack_bf16(xa[t], xb[t]);
    if (c < 11){
      const float4* ap2 = ap + (c + 1) * 16;
      #pragma unroll
      for (int t = 0; t < 2; ++t){ xa[t] = ap2[t * 8 + q * 2]; xb[t] = ap2[t * 8 + q * 2 + 1]; }
    }
    #pragma unroll
    for (int t = 0; t < 2; ++t){
      #pragma unroll
      for (int b = 0; b < 4; ++b){
        short8 bf = *(const short8*)(cur + (t * 8 + nh * 4 + b) * 512 + lane * 8);
        acc[b] = __builtin_amdgcn_mfma_f32_16x16x32_bf16(af[t], bf, acc[b], 0, 0, 0);
      }
    }
  }

  // ---- relu+bias -> hid A-frags in tail ----
  // D: tok_m = q*4+r, n = 16*nb+ln; A2-frag addr: T=n>>5, L2=16*((n>>3)&3)+tok_m, j=n&7
  #pragma unroll
  for (int b = 0; b < 4; ++b){
    int nb = nh * 4 + b;
    int t2 = nb >> 1;
    int q2 = ((nb & 1) << 1) | (ln >> 3);
    int j  = ln & 7;
    #pragma unroll
    for (int r = 0; r < 4; ++r){
      float v = fmaxf(acc[b][r] + b1v[b], 0.0f);
      int L2 = (q2 << 4) | (q * 4 + r);
      hidf[m * 2048 + t2 * 512 + L2 * 8 + j] = (u16)(__float_as_uint(v) >> 16);
    }
  }
  __syncthreads();

  // ---- GEMM2: logits = hid @ W2 + b2; N-blocks split 7/6 across nh groups ----
  short8 a2[4];
  #pragma unroll
  for (int t = 0; t < 4; ++t) a2[t] = *(const short8*)(hidf + m * 2048 + t * 512 + lane * 8);
  const int nb2 = 7 - nh;               // nh=0: b-blocks 0..6, nh=1: 7..12
  float b2v[7];
  #pragma unroll
  for (int bb = 0; bb < 7; ++bb){
    int n = (nh * 7 + bb) * 16 + ln;
    b2v[bb] = (bb < nb2 && n < 200) ? b2[n] : 0.0f;
  }
  f32x4 acc2[7];
  #pragma unroll
  for (int bb = 0; bb < 7; ++bb) acc2[bb] = (f32x4)0.0f;
  #pragma unroll
  for (int bb = 0; bb < 7; ++bb){
    if (bb < nb2){
      #pragma unroll
      for (int t = 0; t < 4; ++t){
        short8 bf = *(const short8*)(w2f + (size_t)(t * 13 + nh * 7 + bb) * 512 + lane * 8);
        acc2[bb] = __builtin_amdgcn_mfma_f32_16x16x32_bf16(a2[t], bf, acc2[bb], 0, 0, 0);
      }
    }
  }

  // dump logits bf16 into buf0 of wbuf (staging fully dead): [32 tok][212]
  #pragma unroll
  for (int bb = 0; bb < 7; ++bb){
    if (bb < nb2){
      #pragma unroll
      for (int r = 0; r < 4; ++r){
        float v = acc2[bb][r] + b2v[bb];
        int tk = m * 16 + q * 4 + r;
        int n  = (nh * 7 + bb) * 16 + ln;
        wbuf[tk * 212 + n] = (u16)(__float_as_uint(v) >> 16);
      }
    }
  }
  __syncthreads();

  // ---- softmax + expected digit: 32 tok x 20 slots = 640 tasks ----
  #pragma unroll
  for (int i = 0; i < 3; ++i){
    int task = tid + i * 256;
    if (task < 640){
      int tok = task / 20, slot = task % 20;
      const u16* lp = wbuf + tok * 212 + slot * 10;
      float v[10];
      #pragma unroll
      for (int k = 0; k < 10; ++k) v[k] = bf2f(lp[k]);
      float mx = v[0];
      #pragma unroll
      for (int k = 1; k < 10; ++k) mx = fmaxf(mx, v[k]);
      float s = 0.0f, sd = 0.0f;
      #pragma unroll
      for (int k = 0; k < 10; ++k){
        float e = __expf(v[k] - mx);
        s += e; sd += e * (float)k;
      }
      float dig = sd / s;
      digits_s[tok * 20 + slot] = dig;
      int gt = tok0 + tok;
      int o = slot / 10, k10 = slot % 10;
      dout[(size_t)25165824 + (size_t)o * 327680 + (size_t)gt * 10 + k10] = dig;
    }
  }
  __syncthreads();

  // ---- t_p = sum_k d_k * (10^k mod p): 32 tok x 2 x 9 = 576 tasks ----
  #pragma unroll
  for (int i = 0; i < 3; ++i){
    int task = tid + i * 256;
    if (task < 576){
      int tok = task / 18, rm = task % 18;
      int ab = rm / 9, pi = rm % 9;
      float t = 0.0f;
      #pragma unroll
      for (int k = 0; k < 10; ++k) t += digits_s[tok * 20 + ab * 10 + k] * POW10F[pi][k];
      tab_s[tok * 18 + ab * 9 + pi] = t;
    }
  }
  __syncthreads();

  // ---- residue arithmetic, 5 ops x 32 tok = 160 tasks ----
  {
    constexpr int PR[9] = {7, 11, 13, 17, 19, 23, 29, 31, 37};
    constexpr u64 CRTC[9] = {
      35336848261ull, 224870852570ull, 114165202074ull, 218257003965ull,
      78113032998ull, 53773464745ull, 68236672504ull, 223420072876ull, 220616539143ull
    };
    if (tid < 160){
      int o5 = tid >> 5, tok = tid & 31;
      u64 acc64 = 0;
      #pragma unroll
      for (int pi = 0; pi < 9; ++pi){
        const int p = PR[pi];
        float ta = tab_s[tok * 18 + pi], tb = tab_s[tok * 18 + 9 + pi];
        int r;
        if (o5 == 0){
          r = __float2int_rn(ta + tb) % p;
        } else if (o5 == 1){
          int s = __float2int_rn(ta - tb) % p;
          r = (s < 0) ? s + p : s;
        } else {
          int ra = __float2int_rn(ta) % p;
          int rb = __float2int_rn(tb) % p;
          if (o5 == 2) r = (ra * rb) % p;
          else if (o5 == 3) r = modpow6(ra, rb, p);
          else r = (rb == 0) ? 0 : (ra * modpow6(rb, p - 2, p)) % p;
        }
        acc64 += (u64)r * CRTC[pi];
      }
      u64 n = acc64 % M_TOTAL;
      int sign = 0;
      u64 un = n;
      if (o5 == 1 && n > M_HALF){ sign = 1; un = M_TOTAL - n; }
      u64 pk = 0;
      #pragma unroll
      for (int k = 0; k < 10; ++k){ pk |= (un % 10ull) << (4 * k); un /= 10ull; }
      pk |= ((u64)sign) << 40;
      ops_s[tok * 5 + o5] = pk;
    }
  }
  __syncthreads();

  // ---- select + MSB-reorder -> msbv[tok][0..11] floats ----
  if (tid < 32){
    int tok = tid;
    u64 pk = (op >= 0) ? ops_s[tok * 5 + op] : 0ull;
    int g[10]; int hi = -1;
    #pragma unroll
    for (int k = 0; k < 10; ++k){
      g[k] = (int)((pk >> (4 * k)) & 15ull);
      if (g[k] != 0) hi = k;
    }
    int ns = (hi >= 0) ? hi + 1 : 1;
    #pragma unroll
    for (int i = 0; i < 10; ++i)
      msbv[tok * 12 + i] = (i < ns) ? (float)g[ns - 1 - i] : -1.0f;
    msbv[tok * 12 + 10] = (float)((pk >> 40) & 1ull);
    msbv[tok * 12 + 11] = 0.0f;
  }
  __syncthreads();

  // ---- epilogue: h_prime = h + G * (msb @ Winj + binj); Winj/binj straight from L1/L2 ----
  if (tid < 192){
    float4 wv[11];
    #pragma unroll
    for (int j = 0; j < 11; ++j) wv[j] = *(const float4*)(Winj + (size_t)j * 768 + tid * 4);
    float4 bj = *(const float4*)(binj + tid * 4);
    const size_t base = (size_t)tok0 * 768 + tid * 4;
    #pragma unroll 4
    for (int tt = 0; tt < 32; ++tt){
      float4 m0 = *(const float4*)(msbv + tt * 12);
      float4 m1 = *(const float4*)(msbv + tt * 12 + 4);
      float4 m2 = *(const float4*)(msbv + tt * 12 + 8);
      float4 hv = *(const float4*)(h + base + (size_t)tt * 768);
      float ix = bj.x, iy = bj.y, iz = bj.z, iw = bj.w;
      ix += m0.x*wv[0].x + m0.y*wv[1].x + m0.z*wv[2].x + m0.w*wv[3].x
          + m1.x*wv[4].x + m1.y*wv[5].x + m1.z*wv[6].x + m1.w*wv[7].x
          + m2.x*wv[8].x + m2.y*wv[9].x + m2.z*wv[10].x;
      iy += m0.x*wv[0].y + m0.y*wv[1].y + m0.z*wv[2].y + m0.w*wv[3].y
          + m1.x*wv[4].y + m1.y*wv[5].y + m1.z*wv[6].y + m1.w*wv[7].y
          + m2.x*wv[8].y + m2.y*wv[9].y + m2.z*wv[10].y;
      iz += m0.x*wv[0].z + m0.y*wv[1].z + m0.z*wv[2].z + m0.w*wv[3].z
          + m1.x*wv[4].z + m1.y*wv[5].z + m1.z*wv[6].z + m1.w*wv[7].z
          + m2.x*wv[8].z + m2.y*wv[9].z + m2.z*wv[10].z;
      iw += m0.x*wv[0].w + m0.y*wv[1].w + m0.z*wv[2].w + m0.w*wv[3].w
          + m1.x*wv[4].w + m1.y*wv[5].w + m1.z*wv[6].w + m1.w*wv[7].w
          + m2.x*wv[8].w + m2.y*wv[9].w + m2.z*wv[10].w;
      float4 o;
      o.x = hv.x + G * ix; o.y = hv.y + G * iy;
      o.z = hv.z + G * iz; o.w = hv.w + G * iw;
      *(float4*)(dout + base + (size_t)tt * 768) = o;
    }
  }
}

// ---------------- launch ----------------
extern "C" void kernel_launch(void* const* d_in, const int* in_sizes, int n_in,
                              void* d_out, int out_size, void* d_ws, size_t ws_size,
                              hipStream_t stream){
  const float* h    = (const float*)d_in[0];
  const float* W1   = (const float*)d_in[1];
  const float* b1   = (const float*)d_in[2];
  const float* W2   = (const float*)d_in[3];
  const float* b2   = (const float*)d_in[4];
  const float* Winj = (const float*)d_in[5];
  const float* binj = (const float*)d_in[6];
  const float* gate = (const float*)d_in[7];
  const int*   ids  = (const int*)d_in[8];
  float* dout = (float*)d_out;

  char* ws = (char*)d_ws;
  int*   op_idx = (int*)(ws + 0);                 // 16 ints
  float* has_eq = (float*)(ws + 64);              // 16 floats
  u16*   w1f    = (u16*)(ws + 256);               // 196608 B
  u16*   w2f    = (u16*)(ws + 256 + 196608);      // 53248 B

  prelude_kernel<<<77, 256, 0, stream>>>(ids, W1, W2, op_idx, has_eq, w1f, w2f);
  mega_kernel<<<1024, 256, 0, stream>>>(h, w1f, w2f, b1, b2, Winj, binj, gate,
                                        op_idx, has_eq, dout);
}

// Round 2
// 316.269 us; speedup vs baseline: 1.0205x; 1.0205x over previous
//
#include <hip/hip_runtime.h>

typedef unsigned short u16;
typedef unsigned int   u32;
typedef unsigned long long u64;

typedef __attribute__((ext_vector_type(8))) short short8;
typedef __attribute__((ext_vector_type(4))) float f32x4;

#define DEV static __device__ __forceinline__

// POW10F[p][k] = 10^k mod p  (primes 7,11,13,17,19,23,29,31,37)
__constant__ float POW10F[9][10] = {
  {1,3,2,6,4,5,1,3,2,6},
  {1,10,1,10,1,10,1,10,1,10},
  {1,10,9,12,3,4,1,10,9,12},
  {1,10,15,14,4,6,9,5,16,7},
  {1,10,5,12,6,3,11,15,17,18},
  {1,10,8,11,18,19,6,14,2,20},
  {1,10,13,14,24,8,22,17,25,18},
  {1,10,7,8,18,25,2,20,14,16},
  {1,10,26,1,10,26,1,10,26,1},
};

#define M_TOTAL  247357937827ull
#define M_HALF   123678968913ull

DEV u16 f2bf_rne(float f){
  u32 u = __float_as_uint(f);
  return (u16)((u + 0x7FFFu + ((u >> 16) & 1u)) >> 16);
}
DEV float bf2f(u16 v){ return __uint_as_float(((u32)v) << 16); }

DEV short8 pack_bf16(float4 a, float4 b){
  union { short8 s; u32 u[4]; } r;
  r.u[0] = (__float_as_uint(a.x) >> 16) | (__float_as_uint(a.y) & 0xFFFF0000u);
  r.u[1] = (__float_as_uint(a.z) >> 16) | (__float_as_uint(a.w) & 0xFFFF0000u);
  r.u[2] = (__float_as_uint(b.x) >> 16) | (__float_as_uint(b.y) & 0xFFFF0000u);
  r.u[3] = (__float_as_uint(b.z) >> 16) | (__float_as_uint(b.w) & 0xFFFF0000u);
  return r.s;
}

DEV void load_lds16(const void* g, void* l){
  __builtin_amdgcn_global_load_lds((const __attribute__((address_space(1))) void*)g,
                                   (__attribute__((address_space(3))) void*)l, 16, 0, 0);
}

DEV int modpow6(int b, int e, int p){
  int res = 1; b %= p;
  #pragma unroll
  for (int i = 0; i < 6; ++i){
    if (e & 1) res = (res * b) % p;
    b = (b * b) % p;
    e >>= 1;
  }
  return res;
}

// ---------------- prelude: per-batch scan (blocks 0..15) + weight repack (16..76) ----------------
__global__ void prelude_kernel(const int* __restrict__ ids, const float* __restrict__ W1,
                               const float* __restrict__ W2, int* __restrict__ op_idx,
                               float* __restrict__ has_eq, u16* __restrict__ w1f,
                               u16* __restrict__ w2f){
  __shared__ int smin[256];
  __shared__ int seq[256];
  int bid = blockIdx.x, tid = threadIdx.x;
  if (bid < 16){
    int b = bid;
    int best = 2048, eq = 0;
    for (int i = tid; i < 2048; i += 256){
      int t = ids[b * 2048 + i];
      if (t >= 20 && t < 25) best = min(best, i);
      eq |= (t == 28) ? 1 : 0;
    }
    smin[tid] = best; seq[tid] = eq;
    __syncthreads();
    for (int s = 128; s > 0; s >>= 1){
      if (tid < s){ smin[tid] = min(smin[tid], smin[tid + s]); seq[tid] |= seq[tid + s]; }
      __syncthreads();
    }
    if (tid == 0){
      int op = -1;
      if (smin[0] < 2048) op = ids[b * 2048 + smin[0]] - 20;
      op_idx[b] = op;
      has_eq[b] = seq[0] ? 1.0f : 0.0f;
    }
  } else {
    int t = (bid - 16) * 256 + tid;   // 0..15615
    if (t < 12288){
      int blk = t >> 6, L = t & 63;
      int T = blk >> 3, b = blk & 7;
      int q = L >> 4, ln = L & 15;
      #pragma unroll
      for (int j = 0; j < 8; ++j){
        int k = 32 * T + 8 * q + j;
        int n = 16 * b + ln;
        w1f[(size_t)blk * 512 + L * 8 + j] = f2bf_rne(W1[k * 128 + n]);
      }
    } else {
      int t2 = t - 12288;             // 0..3327
      int blk = t2 >> 6, L = t2 & 63;
      int ts = blk / 13, b2 = blk % 13;
      int q = L >> 4, ln = L & 15;
      #pragma unroll
      for (int j = 0; j < 8; ++j){
        int k = 32 * ts + 8 * q + j;
        int n = 16 * b2 + ln;
        w2f[(size_t)blk * 512 + L * 8 + j] = (n < 200) ? f2bf_rne(W2[k * 200 + n]) : (u16)0;
      }
    }
  }
}

// ---------------- mega: 64-token blocks, 512 threads (8 waves), K-split GEMM1 ----------------
// LDS 64KB total, 2 blocks/CU = 16 waves/CU:
//  [0,65536): staging (kg0 dbuf [0,32768), kg1 dbuf [32768,65536))
//  part (f32 partial sums, 33268B) overlays [0,33280) after GEMM1
//  hidf [4][2048]u16 (16KB) at 34816 (over dead kg1 buf0)
//  logits [4][4096]u16 (32KB) at 0 (over dead part)
//  digits/tab/ops/msbv overlay hidf region after a2 frags consumed
__launch_bounds__(512, 4)
__global__ void mega_kernel(const float* __restrict__ h, const u16* __restrict__ w1f,
                            const u16* __restrict__ w2f, const float* __restrict__ b1,
                            const float* __restrict__ b2, const float* __restrict__ Winj,
                            const float* __restrict__ binj, const float* __restrict__ gate,
                            const int* __restrict__ op_idx_ws, const float* __restrict__ has_eq_ws,
                            float* __restrict__ dout){
  __shared__ __align__(16) char lds[65536];
  u16*   wbuf     = (u16*)lds;                  // staging (u16 units), later logits
  float* part     = (float*)lds;                // partial K-sums (stride 130, <=2-way banks)
  u16*   hidf     = (u16*)(lds + 34816);        // [4][2048] u16 = 16KB
  float* digits_s = (float*)(lds + 34816);      // [64][20] 5120B (over hidf, dead by then)
  float* tab_s    = (float*)(lds + 39936);      // [64][18] 4608B
  u64*   ops_s    = (u64*)(lds + 44544);        // [64][5]  2560B
  float* msbv     = (float*)(lds + 47104);      // [64][12] 3072B

  const int tid  = threadIdx.x;
  const int w    = tid >> 6;
  const int lane = tid & 63;
  const int ln   = lane & 15, q = lane >> 4;
  const int mw   = w & 3;        // M-tile (16 tokens)
  const int kg   = w >> 2;       // K-group: kg*384 .. +384
  const int wg   = blockIdx.x;
  const int tok0 = wg * 64;
  const int gtok = tok0 + mw * 16 + ln;
  const int batch = wg >> 5;     // 32 blocks per batch

  const int   op = op_idx_ws[batch];
  const float G  = has_eq_ws[batch] * (1.0f / (1.0f + __expf(-gate[0])));

  float b1v[8];
  #pragma unroll
  for (int b = 0; b < 8; ++b) b1v[b] = b1[ln + 16 * b];

  // ---- GEMM1: hid = relu(h @ W1 + b1); K split in 2, 6 chunks of 64 per group ----
  f32x4 acc[8];
  #pragma unroll
  for (int b = 0; b < 8; ++b) acc[b] = (f32x4)0.0f;

  const float4* ap = (const float4*)(h + (size_t)gtok * 768);
  u16* mybuf = wbuf + kg * 16384;              // this K-group's 2x8192-u16 dbuf

  float4 xa[2], xb[2];
  // prologue: stage chunk (kg*6) into buf0, load h chunk (kg*6)
  #pragma unroll
  for (int i = 0; i < 4; ++i){
    int bl = mw * 4 + i;                        // 16 LDS blocks of 1KB per chunk
    int T  = (kg * 6) * 2 + (bl >> 3);
    load_lds16(w1f + (size_t)(T * 8 + (bl & 7)) * 512 + lane * 8, mybuf + bl * 512);
  }
  {
    const float4* ap0 = ap + (kg * 6) * 16;
    #pragma unroll
    for (int t = 0; t < 2; ++t){ xa[t] = ap0[t * 8 + q * 2]; xb[t] = ap0[t * 8 + q * 2 + 1]; }
  }

  #pragma unroll
  for (int cl = 0; cl < 6; ++cl){
    __syncthreads();                            // drains chunk staging + h loads
    const u16* cur = mybuf + (cl & 1) * 8192;
    if (cl < 5){
      u16* nxt = mybuf + ((cl + 1) & 1) * 8192;
      #pragma unroll
      for (int i = 0; i < 4; ++i){
        int bl = mw * 4 + i;
        int T  = (kg * 6 + cl + 1) * 2 + (bl >> 3);
        load_lds16(w1f + (size_t)(T * 8 + (bl & 7)) * 512 + lane * 8, nxt + bl * 512);
      }
    }
    short8 af[2];
    #pragma unroll
    for (int t = 0; t < 2; ++t) af[t] = pack_bf16(xa[t], xb[t]);
    if (cl < 5){
      const float4* ap2 = ap + (kg * 6 + cl + 1) * 16;
      #pragma unroll
      for (int t = 0; t < 2; ++t){ xa[t] = ap2[t * 8 + q * 2]; xb[t] = ap2[t * 8 + q * 2 + 1]; }
    }
    #pragma unroll
    for (int t = 0; t < 2; ++t){
      #pragma unroll
      for (int b = 0; b < 8; ++b){
        short8 bf = *(const short8*)(cur + (t * 8 + b) * 512 + lane * 8);
        acc[b] = __builtin_amdgcn_mfma_f32_16x16x32_bf16(af[t], bf, acc[b], 0, 0, 0);
      }
    }
  }

  // ---- K-reduction through LDS: kg1 writes partials, kg0 adds ----
  __syncthreads();                              // all LDS reads of staging done
  if (kg == 1){
    #pragma unroll
    for (int b = 0; b < 8; ++b){
      #pragma unroll
      for (int r = 0; r < 4; ++r)
        part[mw * 2080 + (q * 4 + r) * 130 + 16 * b + ln] = acc[b][r];
    }
  }
  __syncthreads();

  // ---- relu+bias -> hid A-frags (kg0 waves own the final sums) ----
  // D: tok_m = q*4+r, n = 16b+ln; A2-frag addr: t2=n>>5, L2=16*((n>>3)&3)+tok_m, j=n&7
  if (kg == 0){
    #pragma unroll
    for (int b = 0; b < 8; ++b){
      int t2 = b >> 1;
      int q2 = ((b & 1) << 1) | (ln >> 3);
      int j  = ln & 7;
      #pragma unroll
      for (int r = 0; r < 4; ++r){
        float v = acc[b][r] + part[mw * 2080 + (q * 4 + r) * 130 + 16 * b + ln];
        v = fmaxf(v + b1v[b], 0.0f);
        int L2 = (q2 << 4) | (q * 4 + r);
        hidf[mw * 2048 + t2 * 512 + L2 * 8 + j] = (u16)(__float_as_uint(v) >> 16);
      }
    }
  }
  __syncthreads();

  // ---- GEMM2: logits = hid @ W2 + b2; N-blocks split 7/6 across kg groups ----
  short8 a2[4];
  #pragma unroll
  for (int t = 0; t < 4; ++t) a2[t] = *(const short8*)(hidf + mw * 2048 + t * 512 + lane * 8);
  const int nb2 = 7 - kg;                       // kg0: blocks 0..6, kg1: 7..12
  float b2v[7];
  #pragma unroll
  for (int bb = 0; bb < 7; ++bb){
    int n = (kg * 7 + bb) * 16 + ln;
    b2v[bb] = (bb < nb2 && n < 200) ? b2[n] : 0.0f;
  }
  f32x4 acc2[7];
  #pragma unroll
  for (int bb = 0; bb < 7; ++bb) acc2[bb] = (f32x4)0.0f;
  #pragma unroll
  for (int bb = 0; bb < 7; ++bb){
    if (bb < nb2){
      #pragma unroll
      for (int t = 0; t < 4; ++t){
        short8 bf = *(const short8*)(w2f + (size_t)(t * 13 + kg * 7 + bb) * 512 + lane * 8);
        acc2[bb] = __builtin_amdgcn_mfma_f32_16x16x32_bf16(a2[t], bf, acc2[bb], 0, 0, 0);
      }
    }
  }

  // dump logits bf16 into wbuf (staging + part fully dead): [4 mtile][16 tok][212]
  #pragma unroll
  for (int bb = 0; bb < 7; ++bb){
    if (bb < nb2){
      #pragma unroll
      for (int r = 0; r < 4; ++r){
        float v = acc2[bb][r] + b2v[bb];
        wbuf[mw * 4096 + (q * 4 + r) * 212 + (kg * 7 + bb) * 16 + ln] =
            (u16)(__float_as_uint(v) >> 16);
      }
    }
  }
  __syncthreads();

  // ---- softmax + expected digit: 64 tok x 20 slots = 1280 tasks ----
  #pragma unroll
  for (int i = 0; i < 3; ++i){
    int task = tid + i * 512;
    if (task < 1280){
      int tok = task / 20, slot = task % 20;
      const u16* lp = wbuf + (tok >> 4) * 4096 + (tok & 15) * 212 + slot * 10;
      float v[10];
      #pragma unroll
      for (int k = 0; k < 10; ++k) v[k] = bf2f(lp[k]);
      float mx = v[0];
      #pragma unroll
      for (int k = 1; k < 10; ++k) mx = fmaxf(mx, v[k]);
      float s = 0.0f, sd = 0.0f;
      #pragma unroll
      for (int k = 0; k < 10; ++k){
        float e = __expf(v[k] - mx);
        s += e; sd += e * (float)k;
      }
      float dig = sd / s;
      digits_s[tok * 20 + slot] = dig;
      int gt = tok0 + tok;
      int o = slot / 10, k10 = slot % 10;
      dout[(size_t)25165824 + (size_t)o * 327680 + (size_t)gt * 10 + k10] = dig;
    }
  }
  __syncthreads();

  // ---- t_p = sum_k d_k * (10^k mod p): 64 tok x 2 x 9 = 1152 tasks ----
  #pragma unroll
  for (int i = 0; i < 3; ++i){
    int task = tid + i * 512;
    if (task < 1152){
      int tok = task / 18, rm = task % 18;
      int ab = rm / 9, pi = rm % 9;
      float t = 0.0f;
      #pragma unroll
      for (int k = 0; k < 10; ++k) t += digits_s[tok * 20 + ab * 10 + k] * POW10F[pi][k];
      tab_s[tok * 18 + ab * 9 + pi] = t;
    }
  }
  __syncthreads();

  // ---- residue arithmetic, 5 ops x 64 tok = 320 tasks ----
  {
    constexpr int PR[9] = {7, 11, 13, 17, 19, 23, 29, 31, 37};
    constexpr u64 CRTC[9] = {
      35336848261ull, 224870852570ull, 114165202074ull, 218257003965ull,
      78113032998ull, 53773464745ull, 68236672504ull, 223420072876ull, 220616539143ull
    };
    if (tid < 320){
      int o5 = tid >> 6, tok = tid & 63;
      u64 acc64 = 0;
      #pragma unroll
      for (int pi = 0; pi < 9; ++pi){
        const int p = PR[pi];
        float ta = tab_s[tok * 18 + pi], tb = tab_s[tok * 18 + 9 + pi];
        int r;
        if (o5 == 0){
          r = __float2int_rn(ta + tb) % p;
        } else if (o5 == 1){
          int s = __float2int_rn(ta - tb) % p;
          r = (s < 0) ? s + p : s;
        } else {
          int ra = __float2int_rn(ta) % p;
          int rb = __float2int_rn(tb) % p;
          if (o5 == 2) r = (ra * rb) % p;
          else if (o5 == 3) r = modpow6(ra, rb, p);
          else r = (rb == 0) ? 0 : (ra * modpow6(rb, p - 2, p)) % p;
        }
        acc64 += (u64)r * CRTC[pi];
      }
      u64 n = acc64 % M_TOTAL;
      int sign = 0;
      u64 un = n;
      if (o5 == 1 && n > M_HALF){ sign = 1; un = M_TOTAL - n; }
      u64 pk = 0;
      #pragma unroll
      for (int k = 0; k < 10; ++k){ pk |= (un % 10ull) << (4 * k); un /= 10ull; }
      pk |= ((u64)sign) << 40;
      ops_s[tok * 5 + o5] = pk;
    }
  }
  __syncthreads();

  // ---- select + MSB-reorder -> msbv[tok][0..11] floats ----
  if (tid < 64){
    int tok = tid;
    u64 pk = (op >= 0) ? ops_s[tok * 5 + op] : 0ull;
    int g[10]; int hi = -1;
    #pragma unroll
    for (int k = 0; k < 10; ++k){
      g[k] = (int)((pk >> (4 * k)) & 15ull);
      if (g[k] != 0) hi = k;
    }
    int ns = (hi >= 0) ? hi + 1 : 1;
    #pragma unroll
    for (int i = 0; i < 10; ++i)
      msbv[tok * 12 + i] = (i < ns) ? (float)g[ns - 1 - i] : -1.0f;
    msbv[tok * 12 + 10] = (float)((pk >> 40) & 1ull);
    msbv[tok * 12 + 11] = 0.0f;
  }
  __syncthreads();

  // ---- epilogue: h_prime = h + G * (msb @ Winj + binj); 2 teams x 32 tokens ----
  if (tid < 384){
    const int team = tid / 192;
    const int col  = tid % 192;
    float4 wv[11];
    #pragma unroll
    for (int j = 0; j < 11; ++j) wv[j] = *(const float4*)(Winj + (size_t)j * 768 + col * 4);
    float4 bj = *(const float4*)(binj + col * 4);
    const int t0 = team * 32;
    const size_t base = (size_t)(tok0 + t0) * 768 + col * 4;
    #pragma unroll 4
    for (int tt = 0; tt < 32; ++tt){
      float4 m0 = *(const float4*)(msbv + (t0 + tt) * 12);
      float4 m1 = *(const float4*)(msbv + (t0 + tt) * 12 + 4);
      float4 m2 = *(const float4*)(msbv + (t0 + tt) * 12 + 8);
      float4 hv = *(const float4*)(h + base + (size_t)tt * 768);
      float ix = bj.x, iy = bj.y, iz = bj.z, iw = bj.w;
      ix += m0.x*wv[0].x + m0.y*wv[1].x + m0.z*wv[2].x + m0.w*wv[3].x
          + m1.x*wv[4].x + m1.y*wv[5].x + m1.z*wv[6].x + m1.w*wv[7].x
          + m2.x*wv[8].x + m2.y*wv[9].x + m2.z*wv[10].x;
      iy += m0.x*wv[0].y + m0.y*wv[1].y + m0.z*wv[2].y + m0.w*wv[3].y
          + m1.x*wv[4].y + m1.y*wv[5].y + m1.z*wv[6].y + m1.w*wv[7].y
          + m2.x*wv[8].y + m2.y*wv[9].y + m2.z*wv[10].y;
      iz += m0.x*wv[0].z + m0.y*wv[1].z + m0.z*wv[2].z + m0.w*wv[3].z
          + m1.x*wv[4].z + m1.y*wv[5].z + m1.z*wv[6].z + m1.w*wv[7].z
          + m2.x*wv[8].z + m2.y*wv[9].z + m2.z*wv[10].z;
      iw += m0.x*wv[0].w + m0.y*wv[1].w + m0.z*wv[2].w + m0.w*wv[3].w
          + m1.x*wv[4].w + m1.y*wv[5].w + m1.z*wv[6].w + m1.w*wv[7].w
          + m2.x*wv[8].w + m2.y*wv[9].w + m2.z*wv[10].w;
      float4 o;
      o.x = hv.x + G * ix; o.y = hv.y + G * iy;
      o.z = hv.z + G * iz; o.w = hv.w + G * iw;
      *(float4*)(dout + base + (size_t)tt * 768) = o;
    }
  }
}

// ---------------- launch ----------------
extern "C" void kernel_launch(void* const* d_in, const int* in_sizes, int n_in,
                              void* d_out, int out_size, void* d_ws, size_t ws_size,
                              hipStream_t stream){
  const float* h    = (const float*)d_in[0];
  const float* W1   = (const float*)d_in[1];
  const float* b1   = (const float*)d_in[2];
  const float* W2   = (const float*)d_in[3];
  const float* b2   = (const float*)d_in[4];
  const float* Winj = (const float*)d_in[5];
  const float* binj = (const float*)d_in[6];
  const float* gate = (const float*)d_in[7];
  const int*   ids  = (const int*)d_in[8];
  float* dout = (float*)d_out;

  char* ws = (char*)d_ws;
  int*   op_idx = (int*)(ws + 0);                 // 16 ints
  float* has_eq = (float*)(ws + 64);              // 16 floats
  u16*   w1f    = (u16*)(ws + 256);               // 196608 B
  u16*   w2f    = (u16*)(ws + 256 + 196608);      // 53248 B

  prelude_kernel<<<77, 256, 0, stream>>>(ids, W1, W2, op_idx, has_eq, w1f, w2f);
  mega_kernel<<<512, 512, 0, stream>>>(h, w1f, w2f, b1, b2, Winj, binj, gate,
                                       op_idx, has_eq, dout);
}

// Round 3
// 280.634 us; speedup vs baseline: 1.1500x; 1.1270x over previous
//
#include <hip/hip_runtime.h>

typedef unsigned short u16;
typedef unsigned int   u32;
typedef unsigned long long u64;

typedef __attribute__((ext_vector_type(8))) short short8;
typedef __attribute__((ext_vector_type(4))) float f32x4;

#define DEV static __device__ __forceinline__

// POW10F[p][k] = 10^k mod p  (primes 7,11,13,17,19,23,29,31,37)
__constant__ float POW10F[9][10] = {
  {1,3,2,6,4,5,1,3,2,6},
  {1,10,1,10,1,10,1,10,1,10},
  {1,10,9,12,3,4,1,10,9,12},
  {1,10,15,14,4,6,9,5,16,7},
  {1,10,5,12,6,3,11,15,17,18},
  {1,10,8,11,18,19,6,14,2,20},
  {1,10,13,14,24,8,22,17,25,18},
  {1,10,7,8,18,25,2,20,14,16},
  {1,10,26,1,10,26,1,10,26,1},
};

#define M_TOTAL  247357937827ull
#define M_HALF   123678968913ull

DEV u16 f2bf_rne(float f){
  u32 u = __float_as_uint(f);
  return (u16)((u + 0x7FFFu + ((u >> 16) & 1u)) >> 16);
}
DEV float bf2f(u16 v){ return __uint_as_float(((u32)v) << 16); }

DEV short8 pack_bf16(float4 a, float4 b){
  union { short8 s; u32 u[4]; } r;
  r.u[0] = (__float_as_uint(a.x) >> 16) | (__float_as_uint(a.y) & 0xFFFF0000u);
  r.u[1] = (__float_as_uint(a.z) >> 16) | (__float_as_uint(a.w) & 0xFFFF0000u);
  r.u[2] = (__float_as_uint(b.x) >> 16) | (__float_as_uint(b.y) & 0xFFFF0000u);
  r.u[3] = (__float_as_uint(b.z) >> 16) | (__float_as_uint(b.w) & 0xFFFF0000u);
  return r.s;
}

DEV void load_lds16(const void* g, void* l){
  __builtin_amdgcn_global_load_lds((const __attribute__((address_space(1))) void*)g,
                                   (__attribute__((address_space(3))) void*)l, 16, 0, 0);
}

DEV int modpow6(int b, int e, int p){
  int res = 1; b %= p;
  #pragma unroll
  for (int i = 0; i < 6; ++i){
    if (e & 1) res = (res * b) % p;
    b = (b * b) % p;
    e >>= 1;
  }
  return res;
}

// ---------------- prelude: per-batch scan (blocks 0..15) + weight repack (16..76) ----------------
__global__ void prelude_kernel(const int* __restrict__ ids, const float* __restrict__ W1,
                               const float* __restrict__ W2, int* __restrict__ op_idx,
                               float* __restrict__ has_eq, u16* __restrict__ w1f,
                               u16* __restrict__ w2f){
  __shared__ int smin[256];
  __shared__ int seq[256];
  int bid = blockIdx.x, tid = threadIdx.x;
  if (bid < 16){
    int b = bid;
    int best = 2048, eq = 0;
    for (int i = tid; i < 2048; i += 256){
      int t = ids[b * 2048 + i];
      if (t >= 20 && t < 25) best = min(best, i);
      eq |= (t == 28) ? 1 : 0;
    }
    smin[tid] = best; seq[tid] = eq;
    __syncthreads();
    for (int s = 128; s > 0; s >>= 1){
      if (tid < s){ smin[tid] = min(smin[tid], smin[tid + s]); seq[tid] |= seq[tid + s]; }
      __syncthreads();
    }
    if (tid == 0){
      int op = -1;
      if (smin[0] < 2048) op = ids[b * 2048 + smin[0]] - 20;
      op_idx[b] = op;
      has_eq[b] = seq[0] ? 1.0f : 0.0f;
    }
  } else {
    int t = (bid - 16) * 256 + tid;   // 0..15615
    if (t < 12288){
      int blk = t >> 6, L = t & 63;
      int T = blk >> 3, b = blk & 7;
      int q = L >> 4, ln = L & 15;
      #pragma unroll
      for (int j = 0; j < 8; ++j){
        int k = 32 * T + 8 * q + j;
        int n = 16 * b + ln;
        w1f[(size_t)blk * 512 + L * 8 + j] = f2bf_rne(W1[k * 128 + n]);
      }
    } else {
      int t2 = t - 12288;             // 0..3327
      int blk = t2 >> 6, L = t2 & 63;
      int ts = blk / 13, b2 = blk % 13;
      int q = L >> 4, ln = L & 15;
      #pragma unroll
      for (int j = 0; j < 8; ++j){
        int k = 32 * ts + 8 * q + j;
        int n = 16 * b2 + ln;
        w2f[(size_t)blk * 512 + L * 8 + j] = (n < 200) ? f2bf_rne(W2[k * 200 + n]) : (u16)0;
      }
    }
  }
}

// ---------------- mega: 32-token blocks, 512 threads, h resident in LDS ----------------
// LDS 136KB, 1 block/CU:
//  h_lds [0, 98304): 32 rows x 3072B f32, 16B-swizzled (byte ^= (row&7)<<4)
//  wstg  [98304, 131072): w1f dbuf 2x16KB; buf0 reused as logits [32][212] u16
//  tail  [131072, 139264): hidf [2][2048]u16 -> digits/tab/ops/msbv overlay
__launch_bounds__(512, 2)
__global__ void mega_kernel(const float* __restrict__ h, const u16* __restrict__ w1f,
                            const u16* __restrict__ w2f, const float* __restrict__ b1,
                            const float* __restrict__ b2, const float* __restrict__ Winj,
                            const float* __restrict__ binj, const float* __restrict__ gate,
                            const int* __restrict__ op_idx_ws, const float* __restrict__ has_eq_ws,
                            float* __restrict__ dout){
  __shared__ __align__(16) char lds[139264];
  u16*   wstg     = (u16*)(lds + 98304);       // 16384 u16 (2 x 8192)
  u16*   logit    = (u16*)(lds + 98304);       // [32][212] u16 over buf0
  char*  tail     = lds + 131072;
  u16*   hidf     = (u16*)tail;                // [2][2048] u16 = 8192B
  float* digits_s = (float*)tail;              // [32][20] 2560B (over hidf, dead by then)
  float* tab_s    = (float*)(tail + 2560);     // [32][18] 2304B
  u64*   ops_s    = (u64*)(tail + 4864);       // [32][5]  1280B
  float* msbv     = (float*)(tail + 6144);     // [32][12] 1536B

  const int tid  = threadIdx.x;
  const int w    = tid >> 6;
  const int lane = tid & 63;
  const int ln   = lane & 15, q = lane >> 4;
  const int mw   = w & 1;        // M-tile (16 tokens)
  const int ng   = w >> 1;       // N-group of GEMM1 (32 cols each)
  const int wg   = blockIdx.x;
  const int tok0 = wg * 32;
  const int batch = wg >> 6;     // 64 blocks per batch

  const int   op = op_idx_ws[batch];
  const float G  = has_eq_ws[batch] * (1.0f / (1.0f + __expf(-gate[0])));

  float b1v[2];
  #pragma unroll
  for (int b = 0; b < 2; ++b) b1v[b] = b1[ng * 32 + b * 16 + ln];

  // ---- GEMM1 + fused h->LDS staging; 12 K-chunks of 64, dbuf w1f, 1 barrier/chunk ----
  f32x4 acc[2];
  #pragma unroll
  for (int b = 0; b < 2; ++b) acc[b] = (f32x4)0.0f;

  // h staging: thread handles (row = tid>>4, 16B piece sub = tid&15) per chunk
  const int hrow = tid >> 4, hsub = tid & 15;
  const float* hsrc = h + (size_t)(tok0 + hrow) * 768;
  const int hswz = (hrow & 7) << 4;

  // prologue: chunk0 h -> LDS, chunk1 h -> reg, chunk0 w1f -> LDS
  float4 hr0 = *(const float4*)(hsrc + 0 * 64 + hsub * 4);
  *(float4*)(lds + hrow * 3072 + ((0 * 256 + hsub * 16) ^ hswz)) = hr0;
  float4 hr = *(const float4*)(hsrc + 1 * 64 + hsub * 4);
  #pragma unroll
  for (int i = 0; i < 2; ++i){
    int bl = w * 2 + i;                         // 16 LDS blocks of 1KB per chunk
    load_lds16(w1f + (size_t)(((bl >> 3)) * 8 + (bl & 7)) * 512 + lane * 8,
               wstg + bl * 512);
  }

  const int atok  = mw * 16 + ln;               // this lane's token row for A-frags
  const int aswz  = (atok & 7) << 4;
  const int abase = atok * 3072;

  #pragma unroll
  for (int c = 0; c < 12; ++c){
    __syncthreads();                            // publishes w1f(c) and h(c)
    const u16* cur = wstg + (c & 1) * 8192;
    if (c < 11){
      u16* nxt = wstg + ((c + 1) & 1) * 8192;
      #pragma unroll
      for (int i = 0; i < 2; ++i){
        int bl = w * 2 + i;
        int T  = (c + 1) * 2 + (bl >> 3);
        load_lds16(w1f + (size_t)(T * 8 + (bl & 7)) * 512 + lane * 8, nxt + bl * 512);
      }
      // write h chunk c+1 (loaded last iteration)
      *(float4*)(lds + hrow * 3072 + ((((c + 1) * 256) + hsub * 16) ^ hswz)) = hr;
    }
    if (c < 10) hr = *(const float4*)(hsrc + (c + 2) * 64 + hsub * 4);

    short8 af[2];
    #pragma unroll
    for (int t = 0; t < 2; ++t){
      int byt = c * 256 + t * 128 + q * 32;
      float4 a0 = *(const float4*)(lds + abase + ((byt) ^ aswz));
      float4 a1 = *(const float4*)(lds + abase + ((byt + 16) ^ aswz));
      af[t] = pack_bf16(a0, a1);
    }
    #pragma unroll
    for (int t = 0; t < 2; ++t){
      #pragma unroll
      for (int b = 0; b < 2; ++b){
        short8 bf = *(const short8*)(cur + (t * 8 + ng * 2 + b) * 512 + lane * 8);
        acc[b] = __builtin_amdgcn_mfma_f32_16x16x32_bf16(af[t], bf, acc[b], 0, 0, 0);
      }
    }
  }

  // ---- relu+bias -> hid A2-frags in tail ----
  // D: tok_m = q*4+r, n = 16*nb+ln; A2-frag addr: t2=nb>>1, q2=((nb&1)<<1)|(ln>>3), j=ln&7
  #pragma unroll
  for (int b = 0; b < 2; ++b){
    int nb = ng * 2 + b;
    int t2 = nb >> 1;
    int q2 = ((nb & 1) << 1) | (ln >> 3);
    int j  = ln & 7;
    #pragma unroll
    for (int r = 0; r < 4; ++r){
      float v = fmaxf(acc[b][r] + b1v[b], 0.0f);
      int L2 = (q2 << 4) | (q * 4 + r);
      hidf[mw * 2048 + t2 * 512 + L2 * 8 + j] = (u16)(__float_as_uint(v) >> 16);
    }
  }
  __syncthreads();

  // ---- GEMM2: logits = hid @ W2 + b2; 13 N-blocks split 4/3/3/3 across ng ----
  short8 a2[4];
  #pragma unroll
  for (int t = 0; t < 4; ++t) a2[t] = *(const short8*)(hidf + mw * 2048 + t * 512 + lane * 8);
  const int nstart = (ng == 0) ? 0 : (3 * ng + 1);
  const int ncnt   = (ng == 0) ? 4 : 3;
  float b2v[4];
  #pragma unroll
  for (int bb = 0; bb < 4; ++bb){
    int n = (nstart + bb) * 16 + ln;
    b2v[bb] = (bb < ncnt && n < 200) ? b2[n] : 0.0f;
  }
  f32x4 acc2[4];
  #pragma unroll
  for (int bb = 0; bb < 4; ++bb) acc2[bb] = (f32x4)0.0f;
  #pragma unroll
  for (int bb = 0; bb < 4; ++bb){
    if (bb < ncnt){
      #pragma unroll
      for (int t = 0; t < 4; ++t){
        short8 bf = *(const short8*)(w2f + (size_t)(t * 13 + nstart + bb) * 512 + lane * 8);
        acc2[bb] = __builtin_amdgcn_mfma_f32_16x16x32_bf16(a2[t], bf, acc2[bb], 0, 0, 0);
      }
    }
  }

  // dump logits bf16 into buf0 (w1f staging fully dead): [32 tok][212]
  #pragma unroll
  for (int bb = 0; bb < 4; ++bb){
    if (bb < ncnt){
      #pragma unroll
      for (int r = 0; r < 4; ++r){
        float v = acc2[bb][r] + b2v[bb];
        int tk = mw * 16 + q * 4 + r;
        logit[tk * 212 + (nstart + bb) * 16 + ln] = (u16)(__float_as_uint(v) >> 16);
      }
    }
  }
  __syncthreads();

  // ---- softmax + expected digit: 32 tok x 20 slots = 640 tasks ----
  #pragma unroll
  for (int i = 0; i < 2; ++i){
    int task = tid + i * 512;
    if (task < 640){
      int tok = task / 20, slot = task % 20;
      const u16* lp = logit + tok * 212 + slot * 10;
      float v[10];
      #pragma unroll
      for (int k = 0; k < 10; ++k) v[k] = bf2f(lp[k]);
      float mx = v[0];
      #pragma unroll
      for (int k = 1; k < 10; ++k) mx = fmaxf(mx, v[k]);
      float s = 0.0f, sd = 0.0f;
      #pragma unroll
      for (int k = 0; k < 10; ++k){
        float e = __expf(v[k] - mx);
        s += e; sd += e * (float)k;
      }
      float dig = sd / s;
      digits_s[tok * 20 + slot] = dig;
      int gt = tok0 + tok;
      int o = slot / 10, k10 = slot % 10;
      dout[(size_t)25165824 + (size_t)o * 327680 + (size_t)gt * 10 + k10] = dig;
    }
  }
  __syncthreads();

  // ---- t_p = sum_k d_k * (10^k mod p): 32 tok x 2 x 9 = 576 tasks ----
  #pragma unroll
  for (int i = 0; i < 2; ++i){
    int task = tid + i * 512;
    if (task < 576){
      int tok = task / 18, rm = task % 18;
      int ab = rm / 9, pi = rm % 9;
      float t = 0.0f;
      #pragma unroll
      for (int k = 0; k < 10; ++k) t += digits_s[tok * 20 + ab * 10 + k] * POW10F[pi][k];
      tab_s[tok * 18 + ab * 9 + pi] = t;
    }
  }
  __syncthreads();

  // ---- residue arithmetic, 5 ops x 32 tok = 160 tasks ----
  {
    constexpr int PR[9] = {7, 11, 13, 17, 19, 23, 29, 31, 37};
    constexpr u64 CRTC[9] = {
      35336848261ull, 224870852570ull, 114165202074ull, 218257003965ull,
      78113032998ull, 53773464745ull, 68236672504ull, 223420072876ull, 220616539143ull
    };
    if (tid < 160){
      int o5 = tid >> 5, tok = tid & 31;
      u64 acc64 = 0;
      #pragma unroll
      for (int pi = 0; pi < 9; ++pi){
        const int p = PR[pi];
        float ta = tab_s[tok * 18 + pi], tb = tab_s[tok * 18 + 9 + pi];
        int r;
        if (o5 == 0){
          r = __float2int_rn(ta + tb) % p;
        } else if (o5 == 1){
          int s = __float2int_rn(ta - tb) % p;
          r = (s < 0) ? s + p : s;
        } else {
          int ra = __float2int_rn(ta) % p;
          int rb = __float2int_rn(tb) % p;
          if (o5 == 2) r = (ra * rb) % p;
          else if (o5 == 3) r = modpow6(ra, rb, p);
          else r = (rb == 0) ? 0 : (ra * modpow6(rb, p - 2, p)) % p;
        }
        acc64 += (u64)r * CRTC[pi];
      }
      u64 n = acc64 % M_TOTAL;
      int sign = 0;
      u64 un = n;
      if (o5 == 1 && n > M_HALF){ sign = 1; un = M_TOTAL - n; }
      u64 pk = 0;
      #pragma unroll
      for (int k = 0; k < 10; ++k){ pk |= (un % 10ull) << (4 * k); un /= 10ull; }
      pk |= ((u64)sign) << 40;
      ops_s[tok * 5 + o5] = pk;
    }
  }
  __syncthreads();

  // ---- select + MSB-reorder -> msbv[tok][0..11] floats ----
  if (tid < 32){
    int tok = tid;
    u64 pk = (op >= 0) ? ops_s[tok * 5 + op] : 0ull;
    int g[10]; int hi = -1;
    #pragma unroll
    for (int k = 0; k < 10; ++k){
      g[k] = (int)((pk >> (4 * k)) & 15ull);
      if (g[k] != 0) hi = k;
    }
    int ns = (hi >= 0) ? hi + 1 : 1;
    #pragma unroll
    for (int i = 0; i < 10; ++i)
      msbv[tok * 12 + i] = (i < ns) ? (float)g[ns - 1 - i] : -1.0f;
    msbv[tok * 12 + 10] = (float)((pk >> 40) & 1ull);
    msbv[tok * 12 + 11] = 0.0f;
  }
  __syncthreads();

  // ---- epilogue: h_prime = h + G * (msb @ Winj + binj); h from LDS, store-only HBM ----
  if (tid < 384){
    const int team = tid / 192;                 // 2 teams x 16 tokens
    const int col  = tid % 192;
    float4 wv[11];
    #pragma unroll
    for (int j = 0; j < 11; ++j) wv[j] = *(const float4*)(Winj + (size_t)j * 768 + col * 4);
    float4 bj = *(const float4*)(binj + col * 4);
    const int t0 = team * 16;
    const size_t base = (size_t)(tok0 + t0) * 768 + col * 4;
    #pragma unroll 4
    for (int tt = 0; tt < 16; ++tt){
      int row = t0 + tt;
      float4 m0 = *(const float4*)(msbv + row * 12);
      float4 m1 = *(const float4*)(msbv + row * 12 + 4);
      float4 m2 = *(const float4*)(msbv + row * 12 + 8);
      float4 hv = *(const float4*)(lds + row * 3072 + ((col * 16) ^ ((row & 7) << 4)));
      float ix = bj.x, iy = bj.y, iz = bj.z, iw = bj.w;
      ix += m0.x*wv[0].x + m0.y*wv[1].x + m0.z*wv[2].x + m0.w*wv[3].x
          + m1.x*wv[4].x + m1.y*wv[5].x + m1.z*wv[6].x + m1.w*wv[7].x
          + m2.x*wv[8].x + m2.y*wv[9].x + m2.z*wv[10].x;
      iy += m0.x*wv[0].y + m0.y*wv[1].y + m0.z*wv[2].y + m0.w*wv[3].y
          + m1.x*wv[4].y + m1.y*wv[5].y + m1.z*wv[6].y + m1.w*wv[7].y
          + m2.x*wv[8].y + m2.y*wv[9].y + m2.z*wv[10].y;
      iz += m0.x*wv[0].z + m0.y*wv[1].z + m0.z*wv[2].z + m0.w*wv[3].z
          + m1.x*wv[4].z + m1.y*wv[5].z + m1.z*wv[6].z + m1.w*wv[7].z
          + m2.x*wv[8].z + m2.y*wv[9].z + m2.z*wv[10].z;
      iw += m0.x*wv[0].w + m0.y*wv[1].w + m0.z*wv[2].w + m0.w*wv[3].w
          + m1.x*wv[4].w + m1.y*wv[5].w + m1.z*wv[6].w + m1.w*wv[7].w
          + m2.x*wv[8].w + m2.y*wv[9].w + m2.z*wv[10].w;
      float4 o;
      o.x = hv.x + G * ix; o.y = hv.y + G * iy;
      o.z = hv.z + G * iz; o.w = hv.w + G * iw;
      *(float4*)(dout + base + (size_t)tt * 768) = o;
    }
  }
}

// ---------------- launch ----------------
extern "C" void kernel_launch(void* const* d_in, const int* in_sizes, int n_in,
                              void* d_out, int out_size, void* d_ws, size_t ws_size,
                              hipStream_t stream){
  const float* h    = (const float*)d_in[0];
  const float* W1   = (const float*)d_in[1];
  const float* b1   = (const float*)d_in[2];
  const float* W2   = (const float*)d_in[3];
  const float* b2   = (const float*)d_in[4];
  const float* Winj = (const float*)d_in[5];
  const float* binj = (const float*)d_in[6];
  const float* gate = (const float*)d_in[7];
  const int*   ids  = (const int*)d_in[8];
  float* dout = (float*)d_out;

  char* ws = (char*)d_ws;
  int*   op_idx = (int*)(ws + 0);                 // 16 ints
  float* has_eq = (float*)(ws + 64);              // 16 floats
  u16*   w1f    = (u16*)(ws + 256);               // 196608 B
  u16*   w2f    = (u16*)(ws + 256 + 196608);      // 53248 B

  prelude_kernel<<<77, 256, 0, stream>>>(ids, W1, W2, op_idx, has_eq, w1f, w2f);
  mega_kernel<<<1024, 512, 0, stream>>>(h, w1f, w2f, b1, b2, Winj, binj, gate,
                                        op_idx, has_eq, dout);
}

// Round 4
// 240.059 us; speedup vs baseline: 1.3444x; 1.1690x over previous
//
#include <hip/hip_runtime.h>

typedef unsigned short u16;
typedef unsigned int   u32;
typedef unsigned long long u64;

typedef __attribute__((ext_vector_type(8))) short short8;
typedef __attribute__((ext_vector_type(4))) float f32x4;

#define DEV static __device__ __forceinline__

// POW10F[p][k] = 10^k mod p  (primes 7,11,13,17,19,23,29,31,37)
__constant__ float POW10F[9][10] = {
  {1,3,2,6,4,5,1,3,2,6},
  {1,10,1,10,1,10,1,10,1,10},
  {1,10,9,12,3,4,1,10,9,12},
  {1,10,15,14,4,6,9,5,16,7},
  {1,10,5,12,6,3,11,15,17,18},
  {1,10,8,11,18,19,6,14,2,20},
  {1,10,13,14,24,8,22,17,25,18},
  {1,10,7,8,18,25,2,20,14,16},
  {1,10,26,1,10,26,1,10,26,1},
};

#define M_TOTAL  247357937827ull
#define M_HALF   123678968913ull

DEV u16 f2bf_rne(float f){
  u32 u = __float_as_uint(f);
  return (u16)((u + 0x7FFFu + ((u >> 16) & 1u)) >> 16);
}
DEV float bf2f(u16 v){ return __uint_as_float(((u32)v) << 16); }

DEV short8 pack_bf16(float4 a, float4 b){
  union { short8 s; u32 u[4]; } r;
  r.u[0] = (__float_as_uint(a.x) >> 16) | (__float_as_uint(a.y) & 0xFFFF0000u);
  r.u[1] = (__float_as_uint(a.z) >> 16) | (__float_as_uint(a.w) & 0xFFFF0000u);
  r.u[2] = (__float_as_uint(b.x) >> 16) | (__float_as_uint(b.y) & 0xFFFF0000u);
  r.u[3] = (__float_as_uint(b.z) >> 16) | (__float_as_uint(b.w) & 0xFFFF0000u);
  return r.s;
}

DEV int modpow6(int b, int e, int p){
  int res = 1; b %= p;
  #pragma unroll
  for (int i = 0; i < 6; ++i){
    if (e & 1) res = (res * b) % p;
    b = (b * b) % p;
    e >>= 1;
  }
  return res;
}

// Wave-private phase fence: DS ops complete in order within a wave; lgkmcnt(0)
// guarantees prior LDS writes/reads retired; sched_barrier stops compiler motion.
#define WAVE_SYNC() do { \
  asm volatile("s_waitcnt lgkmcnt(0)" ::: "memory"); \
  __builtin_amdgcn_sched_barrier(0); \
} while (0)

// ---------------- prelude: per-batch scan (blocks 0..15) + weight repack (16..76) ----------------
__global__ void prelude_kernel(const int* __restrict__ ids, const float* __restrict__ W1,
                               const float* __restrict__ W2, int* __restrict__ op_idx,
                               float* __restrict__ has_eq, u16* __restrict__ w1f,
                               u16* __restrict__ w2f){
  __shared__ int smin[256];
  __shared__ int seq[256];
  int bid = blockIdx.x, tid = threadIdx.x;
  if (bid < 16){
    int b = bid;
    int best = 2048, eq = 0;
    for (int i = tid; i < 2048; i += 256){
      int t = ids[b * 2048 + i];
      if (t >= 20 && t < 25) best = min(best, i);
      eq |= (t == 28) ? 1 : 0;
    }
    smin[tid] = best; seq[tid] = eq;
    __syncthreads();
    for (int s = 128; s > 0; s >>= 1){
      if (tid < s){ smin[tid] = min(smin[tid], smin[tid + s]); seq[tid] |= seq[tid + s]; }
      __syncthreads();
    }
    if (tid == 0){
      int op = -1;
      if (smin[0] < 2048) op = ids[b * 2048 + smin[0]] - 20;
      op_idx[b] = op;
      has_eq[b] = seq[0] ? 1.0f : 0.0f;
    }
  } else {
    int t = (bid - 16) * 256 + tid;   // 0..15615
    if (t < 12288){
      int blk = t >> 6, L = t & 63;
      int T = blk >> 3, b = blk & 7;
      int q = L >> 4, ln = L & 15;
      #pragma unroll
      for (int j = 0; j < 8; ++j){
        int k = 32 * T + 8 * q + j;
        int n = 16 * b + ln;
        w1f[(size_t)blk * 512 + L * 8 + j] = f2bf_rne(W1[k * 128 + n]);
      }
    } else {
      int t2 = t - 12288;             // 0..3327
      int blk = t2 >> 6, L = t2 & 63;
      int ts = blk / 13, b2 = blk % 13;
      int q = L >> 4, ln = L & 15;
      #pragma unroll
      for (int j = 0; j < 8; ++j){
        int k = 32 * ts + 8 * q + j;
        int n = 16 * b2 + ln;
        w2f[(size_t)blk * 512 + L * 8 + j] = (n < 200) ? f2bf_rne(W2[k * 200 + n]) : (u16)0;
      }
    }
  }
}

// ---------------- mega: ZERO barriers. Each wave owns 16 tokens end-to-end. ----------------
// B-fragments (w1f/w2f) read straight from global (L2-hot). LDS is wave-private
// scratch only (8KB/wave): hidf shuffle -> logits -> digits/tab/ops/msbv overlays.
__launch_bounds__(256, 2)
__global__ void mega_kernel(const float* __restrict__ h, const u16* __restrict__ w1f,
                            const u16* __restrict__ w2f, const float* __restrict__ b1,
                            const float* __restrict__ b2, const float* __restrict__ Winj,
                            const float* __restrict__ binj, const float* __restrict__ gate,
                            const int* __restrict__ op_idx_ws, const float* __restrict__ has_eq_ws,
                            float* __restrict__ dout){
  __shared__ __align__(16) char lds[32768];

  const int tid  = threadIdx.x;
  const int w    = tid >> 6;
  const int lane = tid & 63;
  const int ln   = lane & 15, q = lane >> 4;
  const int wg   = blockIdx.x;
  const int tok0 = wg * 64;
  const int wtok0 = tok0 + w * 16;     // this wave's first token
  const int batch = wg >> 5;           // 32 blocks per batch

  const int   op = op_idx_ws[batch];
  const float G  = has_eq_ws[batch] * (1.0f / (1.0f + __expf(-gate[0])));

  // wave-private LDS region, 8KB
  char*  wls      = lds + (w << 13);
  u16*   hidf     = (u16*)wls;               // [0,4096): [2048] u16 A2-frags
  u16*   logit    = (u16*)wls;               // [0,6784): [16][212] u16 (hidf dead)
  float* digits_s = (float*)(wls + 6784);    // [6784,8064): [16][20] f32
  float* tab_s    = (float*)wls;             // [0,1152) (logits dead)
  u64*   ops_s    = (u64*)(wls + 1536);      // [1536,2176)
  float* msbv     = (float*)(wls + 2560);    // [2560,3328)

  float b1v[8];
  #pragma unroll
  for (int b = 0; b < 8; ++b) b1v[b] = b1[ln + 16 * b];

  // ---- GEMM1: hid = relu(h @ W1 + b1); B-frags from global w1f, no LDS, no barriers ----
  f32x4 acc[8];
  #pragma unroll
  for (int b = 0; b < 8; ++b) acc[b] = (f32x4)0.0f;

  const float4* ap = (const float4*)(h + (size_t)(wtok0 + ln) * 768);
  float4 xa[2], xb[2];
  #pragma unroll
  for (int t = 0; t < 2; ++t){ xa[t] = ap[t * 8 + q * 2]; xb[t] = ap[t * 8 + q * 2 + 1]; }

  #pragma unroll
  for (int c = 0; c < 12; ++c){
    short8 af[2];
    #pragma unroll
    for (int t = 0; t < 2; ++t) af[t] = pack_bf16(xa[t], xb[t]);
    if (c < 11){
      const float4* ap2 = ap + (c + 1) * 16;
      #pragma unroll
      for (int t = 0; t < 2; ++t){ xa[t] = ap2[t * 8 + q * 2]; xb[t] = ap2[t * 8 + q * 2 + 1]; }
    }
    #pragma unroll
    for (int t = 0; t < 2; ++t){
      #pragma unroll
      for (int b = 0; b < 8; ++b){
        short8 bf = *(const short8*)(w1f + (size_t)(((c * 2 + t) * 8 + b)) * 512 + lane * 8);
        acc[b] = __builtin_amdgcn_mfma_f32_16x16x32_bf16(af[t], bf, acc[b], 0, 0, 0);
      }
    }
  }

  // ---- relu+bias -> hid A2-frags (wave-private LDS shuffle) ----
  // D: tok_m = q*4+r, n = 16b+ln; A2-frag addr: t2=b>>1, q2=((b&1)<<1)|(ln>>3), j=ln&7
  #pragma unroll
  for (int b = 0; b < 8; ++b){
    int t2 = b >> 1;
    int q2 = ((b & 1) << 1) | (ln >> 3);
    int j  = ln & 7;
    #pragma unroll
    for (int r = 0; r < 4; ++r){
      float v = fmaxf(acc[b][r] + b1v[b], 0.0f);
      int L2 = (q2 << 4) | (q * 4 + r);
      hidf[t2 * 512 + L2 * 8 + j] = (u16)(__float_as_uint(v) >> 16);
    }
  }
  WAVE_SYNC();

  // ---- GEMM2: logits = hid @ W2 + b2; full 13 N-blocks per wave ----
  short8 a2[4];
  #pragma unroll
  for (int t = 0; t < 4; ++t) a2[t] = *(const short8*)(hidf + t * 512 + lane * 8);
  WAVE_SYNC();                                // a2 reads retired before logits overwrite

  float b2v[13];
  #pragma unroll
  for (int b = 0; b < 13; ++b){ int n = ln + 16 * b; b2v[b] = (n < 200) ? b2[n] : 0.0f; }
  f32x4 acc2[13];
  #pragma unroll
  for (int b = 0; b < 13; ++b) acc2[b] = (f32x4)0.0f;
  #pragma unroll
  for (int b = 0; b < 13; ++b){
    #pragma unroll
    for (int t = 0; t < 4; ++t){
      short8 bf = *(const short8*)(w2f + (size_t)(t * 13 + b) * 512 + lane * 8);
      acc2[b] = __builtin_amdgcn_mfma_f32_16x16x32_bf16(a2[t], bf, acc2[b], 0, 0, 0);
    }
  }

  // dump logits bf16: [16 tok][212] u16, wave-private
  #pragma unroll
  for (int b = 0; b < 13; ++b){
    #pragma unroll
    for (int r = 0; r < 4; ++r){
      float v = acc2[b][r] + b2v[b];
      logit[(q * 4 + r) * 212 + 16 * b + ln] = (u16)(__float_as_uint(v) >> 16);
    }
  }
  WAVE_SYNC();

  // ---- softmax + expected digit: 16 tok x 20 slots = 320 tasks, 5 per lane ----
  #pragma unroll
  for (int i = 0; i < 5; ++i){
    int task = i * 64 + lane;                 // 0..319
    int tok = task / 20, slot = task % 20;
    const u16* lp = logit + tok * 212 + slot * 10;
    float v[10];
    #pragma unroll
    for (int k = 0; k < 10; ++k) v[k] = bf2f(lp[k]);
    float mx = v[0];
    #pragma unroll
    for (int k = 1; k < 10; ++k) mx = fmaxf(mx, v[k]);
    float s = 0.0f, sd = 0.0f;
    #pragma unroll
    for (int k = 0; k < 10; ++k){
      float e = __expf(v[k] - mx);
      s += e; sd += e * (float)k;
    }
    float dig = sd / s;
    digits_s[tok * 20 + slot] = dig;
    int gt = wtok0 + tok;
    int o = slot / 10, k10 = slot % 10;
    dout[(size_t)25165824 + (size_t)o * 327680 + (size_t)gt * 10 + k10] = dig;
  }
  WAVE_SYNC();

  // ---- t_p = sum_k d_k * (10^k mod p): 16 tok x 2 x 9 = 288 tasks ----
  #pragma unroll
  for (int i = 0; i < 5; ++i){
    int task = i * 64 + lane;
    if (task < 288){
      int tok = task / 18, rm = task % 18;
      int ab = rm / 9, pi = rm % 9;
      float t = 0.0f;
      #pragma unroll
      for (int k = 0; k < 10; ++k) t += digits_s[tok * 20 + ab * 10 + k] * POW10F[pi][k];
      tab_s[tok * 18 + ab * 9 + pi] = t;
    }
  }
  WAVE_SYNC();

  // ---- residue arithmetic, 5 ops x 16 tok = 80 tasks ----
  {
    constexpr int PR[9] = {7, 11, 13, 17, 19, 23, 29, 31, 37};
    constexpr u64 CRTC[9] = {
      35336848261ull, 224870852570ull, 114165202074ull, 218257003965ull,
      78113032998ull, 53773464745ull, 68236672504ull, 223420072876ull, 220616539143ull
    };
    #pragma unroll
    for (int i = 0; i < 2; ++i){
      int task = i * 64 + lane;
      if (task < 80){
        int o5 = task >> 4, tok = task & 15;
        u64 acc64 = 0;
        #pragma unroll
        for (int pi = 0; pi < 9; ++pi){
          const int p = PR[pi];
          float ta = tab_s[tok * 18 + pi], tb = tab_s[tok * 18 + 9 + pi];
          int r;
          if (o5 == 0){
            r = __float2int_rn(ta + tb) % p;
          } else if (o5 == 1){
            int s = __float2int_rn(ta - tb) % p;
            r = (s < 0) ? s + p : s;
          } else {
            int ra = __float2int_rn(ta) % p;
            int rb = __float2int_rn(tb) % p;
            if (o5 == 2) r = (ra * rb) % p;
            else if (o5 == 3) r = modpow6(ra, rb, p);
            else r = (rb == 0) ? 0 : (ra * modpow6(rb, p - 2, p)) % p;
          }
          acc64 += (u64)r * CRTC[pi];
        }
        u64 n = acc64 % M_TOTAL;
        int sign = 0;
        u64 un = n;
        if (o5 == 1 && n > M_HALF){ sign = 1; un = M_TOTAL - n; }
        u64 pk = 0;
        #pragma unroll
        for (int k = 0; k < 10; ++k){ pk |= (un % 10ull) << (4 * k); un /= 10ull; }
        pk |= ((u64)sign) << 40;
        ops_s[tok * 5 + o5] = pk;
      }
    }
  }
  WAVE_SYNC();

  // ---- select + MSB-reorder -> msbv[tok][0..11] ----
  if (lane < 16){
    int tok = lane;
    u64 pk = (op >= 0) ? ops_s[tok * 5 + op] : 0ull;
    int g[10]; int hi = -1;
    #pragma unroll
    for (int k = 0; k < 10; ++k){
      g[k] = (int)((pk >> (4 * k)) & 15ull);
      if (g[k] != 0) hi = k;
    }
    int ns = (hi >= 0) ? hi + 1 : 1;
    #pragma unroll
    for (int i = 0; i < 10; ++i)
      msbv[tok * 12 + i] = (i < ns) ? (float)g[ns - 1 - i] : -1.0f;
    msbv[tok * 12 + 10] = (float)((pk >> 40) & 1ull);
    msbv[tok * 12 + 11] = 0.0f;
  }
  WAVE_SYNC();

  // ---- epilogue: h_prime = h + G * (msb @ Winj + binj); wave-private, 16 rows ----
  {
    const float4* Wj4 = (const float4*)Winj;   // [11][192] float4
    const float4* bj4 = (const float4*)binj;   // [192] float4
    #pragma unroll
    for (int cc = 0; cc < 3; ++cc){
      const int f = cc * 64 + lane;            // float4 column index 0..191
      float4 wv[11];
      #pragma unroll
      for (int j = 0; j < 11; ++j) wv[j] = Wj4[j * 192 + f];
      float4 bj = bj4[f];
      const size_t base = (size_t)wtok0 * 768 + (size_t)f * 4;
      #pragma unroll 4
      for (int row = 0; row < 16; ++row){
        float4 m0 = *(const float4*)(msbv + row * 12);
        float4 m1 = *(const float4*)(msbv + row * 12 + 4);
        float4 m2 = *(const float4*)(msbv + row * 12 + 8);
        float4 hv = *(const float4*)(h + base + (size_t)row * 768);
        float ix = bj.x, iy = bj.y, iz = bj.z, iw = bj.w;
        ix += m0.x*wv[0].x + m0.y*wv[1].x + m0.z*wv[2].x + m0.w*wv[3].x
            + m1.x*wv[4].x + m1.y*wv[5].x + m1.z*wv[6].x + m1.w*wv[7].x
            + m2.x*wv[8].x + m2.y*wv[9].x + m2.z*wv[10].x;
        iy += m0.x*wv[0].y + m0.y*wv[1].y + m0.z*wv[2].y + m0.w*wv[3].y
            + m1.x*wv[4].y + m1.y*wv[5].y + m1.z*wv[6].y + m1.w*wv[7].y
            + m2.x*wv[8].y + m2.y*wv[9].y + m2.z*wv[10].y;
        iz += m0.x*wv[0].z + m0.y*wv[1].z + m0.z*wv[2].z + m0.w*wv[3].z
            + m1.x*wv[4].z + m1.y*wv[5].z + m1.z*wv[6].z + m1.w*wv[7].z
            + m2.x*wv[8].z + m2.y*wv[9].z + m2.z*wv[10].z;
        iw += m0.x*wv[0].w + m0.y*wv[1].w + m0.z*wv[2].w + m0.w*wv[3].w
            + m1.x*wv[4].w + m1.y*wv[5].w + m1.z*wv[6].w + m1.w*wv[7].w
            + m2.x*wv[8].w + m2.y*wv[9].w + m2.z*wv[10].w;
        float4 o;
        o.x = hv.x + G * ix; o.y = hv.y + G * iy;
        o.z = hv.z + G * iz; o.w = hv.w + G * iw;
        *(float4*)(dout + base + (size_t)row * 768) = o;
      }
    }
  }
}

// ---------------- launch ----------------
extern "C" void kernel_launch(void* const* d_in, const int* in_sizes, int n_in,
                              void* d_out, int out_size, void* d_ws, size_t ws_size,
                              hipStream_t stream){
  const float* h    = (const float*)d_in[0];
  const float* W1   = (const float*)d_in[1];
  const float* b1   = (const float*)d_in[2];
  const float* W2   = (const float*)d_in[3];
  const float* b2   = (const float*)d_in[4];
  const float* Winj = (const float*)d_in[5];
  const float* binj = (const float*)d_in[6];
  const float* gate = (const float*)d_in[7];
  const int*   ids  = (const int*)d_in[8];
  float* dout = (float*)d_out;

  char* ws = (char*)d_ws;
  int*   op_idx = (int*)(ws + 0);                 // 16 ints
  float* has_eq = (float*)(ws + 64);              // 16 floats
  u16*   w1f    = (u16*)(ws + 256);               // 196608 B
  u16*   w2f    = (u16*)(ws + 256 + 196608);      // 53248 B

  prelude_kernel<<<77, 256, 0, stream>>>(ids, W1, W2, op_idx, has_eq, w1f, w2f);
  mega_kernel<<<512, 256, 0, stream>>>(h, w1f, w2f, b1, b2, Winj, binj, gate,
                                       op_idx, has_eq, dout);
}